// Round 10
// baseline (45.501 us; speedup 1.0000x reference)
//
#include <hip/hip_runtime.h>
#include <hip/hip_bf16.h>
#include <stdint.h>
#include <math.h>

#define RES     256
#define M_MEAS  8192
#define KDIM    8192
#define ROWSC   2048        // 4 batches * {Re 0..255, Im 256..511}
#define NCOLS   288         // cos u at [0,129)+pad cols 0..143, sin at 144..287
#define SINOFF  144
#define SPLIT   16
#define KCHUNK  512
#define BM      128
#define BN      144
#define BK      64
#define NT      (KCHUNK / BK)   // 8
#define TWO_PI  6.28318530717958647692f

typedef __attribute__((ext_vector_type(8))) __bf16 bf16x8;
typedef __attribute__((ext_vector_type(8))) unsigned short u16x8;
typedef __attribute__((ext_vector_type(4))) float f32x4;
typedef __attribute__((ext_vector_type(2))) float f32x2;

// ---- workspace: Cp bf16[16][2048][288] @0 (18.9 MB) ----

__device__ __forceinline__ float bf2f(unsigned short v) {
    unsigned u = ((unsigned)v) << 16;
    return __uint_as_float(u);
}

// packed f32x2 -> 2xbf16 (RNE); plain casts so compiler can fuse to v_cvt_pk_bf16_f32
__device__ __forceinline__ unsigned pack2bf(float a, float b) {
    unsigned short ha = __bfloat16_as_ushort(__float2bfloat16(a));
    unsigned short hb = __bfloat16_as_ushort(__float2bfloat16(b));
    return (unsigned)ha | ((unsigned)hb << 16);
}

// sbuf layout (floats)
#define SB_KX 0
#define SB_KY 512
#define SB_RE 1024
#define SB_IM 1536

// ---------------- kernel 1: fully-fused split-K GEMM ---------------------------------
// Per block: gather its own s samples, generate A (s*Ey) AND B (Ex trig) tiles on the
// fly in LDS. No staging from global in the K-loop; one barrier per K-step.
__global__ __launch_bounds__(256, 2) void k_gemm(const float* __restrict__ in,
                                                 const float* __restrict__ xs,
                                                 unsigned short* __restrict__ Cp) {
    __shared__ __align__(16) unsigned short As[2][BM * BK];   // 2 x 16 KB
    __shared__ __align__(16) unsigned short Bs[2][BN * BK];   // 2 x 18 KB
    __shared__ __align__(16) float sbuf[4 * 512];             // kx|ky|sRe|sIm, 8 KB

    int bid = blockIdx.x;              // 512 = 2 col * 16 row * 16 split
    int tc = bid & 1, rest = bid >> 1;
    int tr = rest & 15, split = rest >> 4;
    int col0 = tc * BN;
    int kbase = split * KCHUNK;
    int yhalf = tr & 1, isIm = (tr >> 1) & 1, batch = tr >> 2;
    int tid = threadIdx.x;
    int w = tid >> 6, l = tid & 63;
    int lr = l & 15, lu = l >> 4;

    f32x4 acc[2][9] = {};

    // ---- prologue: load kx/ky + gather s for this (batch, kchunk) into sbuf ----
    {
        int i0 = tid * 2;                          // 0..510
        int m = kbase + i0;
        f32x4 xv = *(const f32x4*)(xs + 2 * m);    // kx0,ky0,kx1,ky1 (16B aligned)
        sbuf[SB_KX + i0]     = xv.x;
        sbuf[SB_KY + i0]     = xv.y;
        sbuf[SB_KX + i0 + 1] = xv.z;
        sbuf[SB_KY + i0 + 1] = xv.w;
        const float* img = in + (size_t)batch * RES * RES * 2;
#pragma unroll
        for (int e = 0; e < 2; ++e) {
            float kx = e ? xv.z : xv.x;
            float ky = e ? xv.w : xv.y;
            float gx = (kx * (1.0f / 128.0f) + 1.0f) * 0.5f * 255.0f;
            float gy = (ky * (1.0f / 128.0f) + 1.0f) * 0.5f * 255.0f;
            float fx0 = floorf(gx), fy0 = floorf(gy);
            float wx1 = gx - fx0, wx0 = 1.0f - wx1;
            float wy1 = gy - fy0, wy0 = 1.0f - wy1;
            int x0 = (int)fx0, y0 = (int)fy0;
            float re = 0.0f, im = 0.0f;
#pragma unroll
            for (int dy = 0; dy < 2; ++dy) {
#pragma unroll
                for (int dx = 0; dx < 2; ++dx) {
                    int xi = x0 + dx, yi = y0 + dy;
                    bool v = (xi >= 0) && (xi < RES) && (yi >= 0) && (yi < RES);
                    int xc = min(max(xi, 0), RES - 1);
                    int yc = min(max(yi, 0), RES - 1);
                    float wt = (dx ? wx1 : wx0) * (dy ? wy1 : wy0) * (v ? 1.0f : 0.0f);
                    const float* p = img + (((size_t)yc * RES + xc) * 2);
                    re += p[0] * wt;
                    im += p[1] * wt;
                }
            }
            sbuf[SB_RE + i0 + e] = re;
            sbuf[SB_IM + i0 + e] = im;
        }
    }
    __syncthreads();                               // sbuf complete

    // ---- A generation: lane owns m-pair p, 16 y-rows; sincos once + rotations ----
#define GEN_A(buf, kt)                                                            \
    do {                                                                          \
        int p = tid & 31, g = tid >> 5;                                           \
        int mi = (kt) * BK + p * 2;                                               \
        float2 kyp = *(const float2*)&sbuf[SB_KY + mi];                           \
        float2 srp = *(const float2*)&sbuf[SB_RE + mi];                           \
        float2 sip = *(const float2*)&sbuf[SB_IM + mi];                           \
        float n0 = (float)(yhalf * 128 + g * 16 - 128);                           \
        float c0, s0, c1, s1, cs0, ss0, cs1, ss1;                                 \
        { float u = kyp.x * n0 * (1.0f/256.0f); u -= rintf(u);                    \
          s0 = __sinf(u * TWO_PI); c0 = __cosf(u * TWO_PI); }                     \
        { float u = kyp.x * (1.0f/256.0f); u -= rintf(u);                         \
          ss0 = __sinf(u * TWO_PI); cs0 = __cosf(u * TWO_PI); }                   \
        { float u = kyp.y * n0 * (1.0f/256.0f); u -= rintf(u);                    \
          s1 = __sinf(u * TWO_PI); c1 = __cosf(u * TWO_PI); }                     \
        { float u = kyp.y * (1.0f/256.0f); u -= rintf(u);                         \
          ss1 = __sinf(u * TWO_PI); cs1 = __cosf(u * TWO_PI); }                   \
        _Pragma("unroll")                                                         \
        for (int j = 0; j < 16; ++j) {                                            \
            int r = g * 16 + j;                                                   \
            float v0 = isIm ? fmaf(srp.x, s0, sip.x * c0)                         \
                            : fmaf(srp.x, c0, -(sip.x * s0));                     \
            float v1 = isIm ? fmaf(srp.y, s1, sip.y * c1)                         \
                            : fmaf(srp.y, c1, -(sip.y * s1));                     \
            *(unsigned*)&As[buf][r * 64 + (((p >> 2) ^ (r & 7)) * 8) + (p & 3) * 2] \
                = pack2bf(v0, v1);                                                \
            float nc0 = fmaf(c0, cs0, -(s0 * ss0));                               \
            float ns0 = fmaf(s0, cs0,  (c0 * ss0));                               \
            c0 = nc0; s0 = ns0;                                                   \
            float nc1 = fmaf(c1, cs1, -(s1 * ss1));                               \
            float ns1 = fmaf(s1, cs1,  (c1 * ss1));                               \
            c1 = nc1; s1 = ns1;                                                   \
        }                                                                         \
    } while (0)

    // ---- B generation: lane owns m-pair p, 18 u-rows; value = cos or sin(2pi kx u/256)
#define GEN_B(buf, kt)                                                            \
    do {                                                                          \
        int p = tid & 31, g = tid >> 5;                                           \
        int mi = (kt) * BK + p * 2;                                               \
        float2 kxp = *(const float2*)&sbuf[SB_KX + mi];                           \
        float r0 = (float)(g * 18);                                               \
        float c0, s0, c1, s1, cs0, ss0, cs1, ss1;                                 \
        { float u = kxp.x * r0 * (1.0f/256.0f); u -= rintf(u);                    \
          s0 = __sinf(u * TWO_PI); c0 = __cosf(u * TWO_PI); }                     \
        { float u = kxp.x * (1.0f/256.0f); u -= rintf(u);                         \
          ss0 = __sinf(u * TWO_PI); cs0 = __cosf(u * TWO_PI); }                   \
        { float u = kxp.y * r0 * (1.0f/256.0f); u -= rintf(u);                    \
          s1 = __sinf(u * TWO_PI); c1 = __cosf(u * TWO_PI); }                     \
        { float u = kxp.y * (1.0f/256.0f); u -= rintf(u);                         \
          ss1 = __sinf(u * TWO_PI); cs1 = __cosf(u * TWO_PI); }                   \
        _Pragma("unroll")                                                         \
        for (int j = 0; j < 18; ++j) {                                            \
            int r = g * 18 + j;                                                   \
            float live = (r <= 128) ? 1.0f : 0.0f;                                \
            float v0 = (tc ? s0 : c0) * live;                                     \
            float v1 = (tc ? s1 : c1) * live;                                     \
            *(unsigned*)&Bs[buf][r * 64 + (((p >> 2) ^ (r & 7)) * 8) + (p & 3) * 2] \
                = pack2bf(v0, v1);                                                \
            float nc0 = fmaf(c0, cs0, -(s0 * ss0));                               \
            float ns0 = fmaf(s0, cs0,  (c0 * ss0));                               \
            c0 = nc0; s0 = ns0;                                                   \
            float nc1 = fmaf(c1, cs1, -(s1 * ss1));                               \
            float ns1 = fmaf(s1, cs1,  (c1 * ss1));                               \
            c1 = nc1; s1 = ns1;                                                   \
        }                                                                         \
    } while (0)

    GEN_B(0, 0);
    GEN_A(0, 0);
    __syncthreads();                               // buf0 ready for all waves

    for (int t = 0; t < NT; ++t) {
        int cur = t & 1;
        if (t < NT - 1) {
            GEN_B(cur ^ 1, t + 1);                 // VALU; overlaps other waves' MFMA
            GEN_A(cur ^ 1, t + 1);
        }

        bf16x8 af[2][2], bfr[2][9];
#pragma unroll
        for (int ks = 0; ks < 2; ++ks) {
            int uu = ks * 4 + lu;
#pragma unroll
            for (int i = 0; i < 2; ++i) {
                int r = w * 32 + i * 16 + lr;
                af[ks][i] = *(const bf16x8*)&As[cur][r * 64 + ((uu ^ (r & 7)) * 8)];
            }
#pragma unroll
            for (int j = 0; j < 9; ++j) {
                int r = j * 16 + lr;
                bfr[ks][j] = *(const bf16x8*)&Bs[cur][r * 64 + ((uu ^ (r & 7)) * 8)];
            }
        }
        asm volatile("s_waitcnt lgkmcnt(0)" ::: "memory");   // reads + own GEN writes done
        __builtin_amdgcn_sched_barrier(0);
        __builtin_amdgcn_s_setprio(1);
#pragma unroll
        for (int ks = 0; ks < 2; ++ks)
#pragma unroll
            for (int i = 0; i < 2; ++i)
#pragma unroll
                for (int j = 0; j < 9; ++j)
                    acc[i][j] = __builtin_amdgcn_mfma_f32_16x16x32_bf16(af[ks][i], bfr[ks][j], acc[i][j], 0, 0, 0);
        __builtin_amdgcn_s_setprio(0);
        __builtin_amdgcn_sched_barrier(0);
        __builtin_amdgcn_s_barrier();              // all waves done with cur
    }
#undef GEN_A
#undef GEN_B

    unsigned short* Cb = Cp + (size_t)split * ROWSC * NCOLS;
#pragma unroll
    for (int i = 0; i < 2; ++i) {
#pragma unroll
        for (int j = 0; j < 9; ++j) {
            int colg = col0 + j * 16 + lr;
#pragma unroll
            for (int v = 0; v < 4; ++v) {
                int rowg = tr * BM + w * 32 + i * 16 + lu * 4 + v;
                Cb[(size_t)rowg * NCOLS + colg] =
                    __bfloat16_as_ushort(__float2bfloat16(acc[i][j][v]));
            }
        }
    }
}

// ---------------- kernel 2: block-per-(b,y) cooperative split-K reduce (r9 exact) ----
__global__ __launch_bounds__(256) void k_combine(const unsigned short* __restrict__ Cp,
                                                 float* __restrict__ out) {
    __shared__ float part[4 * 68 * 9];            // 9792 B
    int blk = blockIdx.x;
    int b = blk >> 8, y = blk & 255;
    int tid = threadIdx.x;
    int q = tid >> 6, un = tid & 63;

    size_t rRe = ((size_t)b * 512 + y) * NCOLS;
    size_t rIm = rRe + (size_t)256 * NCOLS;

#pragma unroll
    for (int rep = 0; rep < 2; ++rep) {
        int unit = un + rep * 64;
        if (rep == 1 && un >= 4) break;
        int seg = unit / 17, uidx = unit - seg * 17;
        size_t base = ((seg & 2) ? rIm : rRe) + ((seg & 1) ? SINOFF : 0) + uidx * 8;
        float a[8] = {};
#pragma unroll
        for (int s2 = 0; s2 < 4; ++s2) {
            const unsigned short* Cb = Cp + (size_t)(q * 4 + s2) * ROWSC * NCOLS;
            u16x8 v = *(const u16x8*)(Cb + base);
#pragma unroll
            for (int k = 0; k < 8; ++k) a[k] += bf2f(v[k]);
        }
#pragma unroll
        for (int k = 0; k < 8; ++k) part[(q * 68 + unit) * 9 + k] = a[k];
    }
    __syncthreads();

    if (tid < 68) {
#pragma unroll
        for (int k = 0; k < 8; ++k) {
            float s = part[(0 * 68 + tid) * 9 + k] + part[(1 * 68 + tid) * 9 + k]
                    + part[(2 * 68 + tid) * 9 + k] + part[(3 * 68 + tid) * 9 + k];
            part[tid * 9 + k] = s;
        }
    }
    __syncthreads();

    int x = tid;
    int n = x - 128;
    int u = (n < 0) ? -n : n;
    float sg = (n < 0) ? -1.0f : 1.0f;
    int ui = u >> 3, uk = u & 7;
    float cr = part[(0 * 17 + ui) * 9 + uk];
    float sr = part[(17 + ui) * 9 + uk];
    float ci = part[(34 + ui) * 9 + uk];
    float si = part[(51 + ui) * 9 + uk];
    float re = cr - sg * si;
    float im = sg * sr + ci;
    ((f32x2*)out)[(size_t)(b * 256 + y) * 256 + x] = (f32x2){re, im};
}

extern "C" void kernel_launch(void* const* d_in, const int* in_sizes, int n_in,
                              void* d_out, int out_size, void* d_ws, size_t ws_size,
                              hipStream_t stream) {
    const float* in = (const float*)d_in[0];
    const float* xs = (const float*)d_in[1];
    float* out = (float*)d_out;
    unsigned short* Cp = (unsigned short*)d_ws;

    k_gemm   <<<512,  256, 0, stream>>>(in, xs, Cp);
    k_combine<<<1024, 256, 0, stream>>>(Cp, out);
}